// Round 4
// baseline (86.730 us; speedup 1.0000x reference)
//
#include <hip/hip_runtime.h>

// Problem constants (from reference setup_inputs / OUTPUT_LENGTH)
#define B_SZ 16
#define N_SZ 512
#define C_SZ 512
#define L_SZ 2048
#define ROW4 (C_SZ / 4)          // 128 float4 per row
#define BLK_ROWS 16              // output rows per block
#define THREADS 256
#define GRID (B_SZ * L_SZ / BLK_ROWS)   // 2048 blocks, 128 per batch

// Fully fused: each block recomputes the per-batch duration scan (512 floats,
// L2-resident after the first block of the batch), binary-searches its 16 rows'
// source phonemes, and copies 16 rows x 2 KB with unrolled float4 accesses.
__global__ __launch_bounds__(THREADS) void lenreg_fused_kernel(
    const float4* __restrict__ enc,     // (B, N, C) as float4
    const float*  __restrict__ ldur,    // (B, N, 1)
    float4*       __restrict__ out)     // (B, L, C) as float4
{
    __shared__ int ends[N_SZ];   // inclusive cumsum of durations
    __shared__ int wsum[4];      // per-wave totals
    __shared__ int rowp[BLK_ROWS];

    const int t    = threadIdx.x;
    const int lane = t & 63;
    const int w    = t >> 6;
    const int b    = blockIdx.x >> 7;           // 128 blocks per batch
    const int l0   = (blockIdx.x & 127) << 4;   // first of 16 rows

    // --- durations: dur = floor(2^ld + 1e-4) * (ld > 0), 2 per thread ---
    const int n0 = t * 2, n1 = n0 + 1;
    const float f0 = ldur[b * N_SZ + n0];
    const float f1 = ldur[b * N_SZ + n1];
    const int d0 = (f0 > 0.f) ? (int)floorf(exp2f(f0) + 1e-4f) : 0;
    const int d1 = (f1 > 0.f) ? (int)floorf(exp2f(f1) + 1e-4f) : 0;

    // --- inclusive scan of pair-sums: shuffle within wave, LDS across waves ---
    int scan = d0 + d1;
    #pragma unroll
    for (int o = 1; o < 64; o <<= 1) {
        int v = __shfl_up(scan, o, 64);
        if (lane >= o) scan += v;
    }
    if (lane == 63) wsum[w] = scan;
    __syncthreads();
    int base = 0, total = 0;
    #pragma unroll
    for (int i = 0; i < 4; ++i) {
        const int s = wsum[i];
        if (i < w) base += s;
        total += s;
    }
    const int incl1 = base + scan;   // inclusive cumsum at n1
    ends[n1] = incl1;
    ends[n0] = incl1 - d1;
    __syncthreads();

    // --- 16 threads: binary-search source phoneme for each row ---
    // First p with ends[p] > l. 10 = ceil(log2(513)) iterations guarantees
    // lo == hi on exit (9 left a 1-wide unresolved range -> off-by-one bug).
    if (t < BLK_ROWS) {
        const int l = l0 + t;
        int p = -1;
        if (l < total) {
            int lo = 0, hi = N_SZ;
            #pragma unroll
            for (int it = 0; it < 10; ++it) {
                const int mid = (lo + hi) >> 1;
                if (ends[mid] > l) hi = mid; else lo = mid + 1;
            }
            p = lo;
        }
        rowp[t] = p;
    }
    __syncthreads();

    // --- copy 16 rows x 128 float4 = 2048 float4; 8 per thread, unrolled ---
    const size_t outBase = (size_t)(b * L_SZ + l0) * ROW4;
    const int    encBase = b * N_SZ * ROW4;
    #pragma unroll
    for (int i = 0; i < 8; ++i) {
        const int e  = t + i * THREADS;
        const int r  = e >> 7;            // row within block
        const int c4 = e & (ROW4 - 1);
        const int p  = rowp[r];
        float4 v = make_float4(0.f, 0.f, 0.f, 0.f);
        if (p >= 0) v = enc[encBase + p * ROW4 + c4];
        out[outBase + e] = v;
    }
}

extern "C" void kernel_launch(void* const* d_in, const int* in_sizes, int n_in,
                              void* d_out, int out_size, void* d_ws, size_t ws_size,
                              hipStream_t stream) {
    const float* enc = (const float*)d_in[0];   // (16, 512, 512) fp32
    const float* ld  = (const float*)d_in[1];   // (16, 512, 1)  fp32
    float* out       = (float*)d_out;           // (16, 2048, 512) fp32

    lenreg_fused_kernel<<<GRID, THREADS, 0, stream>>>(
        (const float4*)enc, ld, (float4*)out);
}